// Round 1
// baseline (212.835 us; speedup 1.0000x reference)
//
#include <hip/hip_runtime.h>
#include <hip/hip_bf16.h>

typedef __bf16 bf16_t;
typedef __bf16 bf16x8 __attribute__((ext_vector_type(8)));
typedef float f32x4 __attribute__((ext_vector_type(4)));

constexpr int B = 4, T = 4096, C = 1024, H = 64;

// ---------------------------------------------------------------------------
// Kernel 1: convert weights to bf16, transposed: WT[w][h][c], w in {q,k,v}.
// Fold the 1/sqrt(H)=0.125 attention scale into Wq.
// ---------------------------------------------------------------------------
__global__ __launch_bounds__(256) void wconv_kernel(
    const float* __restrict__ Wk, const float* __restrict__ Wq,
    const float* __restrict__ Wv, bf16_t* __restrict__ WT) {
  int idx = blockIdx.x * 256 + threadIdx.x;
  if (idx >= 3 * H * C) return;
  int w = idx / (H * C);
  int rem = idx - w * H * C;
  int h = rem / C;
  int c = rem - h * C;
  const float* src = (w == 0) ? Wq : (w == 1) ? Wk : Wv;
  float f = src[c * H + h];
  if (w == 0) f *= 0.125f;
  WT[idx] = (bf16_t)f;
}

// ---------------------------------------------------------------------------
// Kernel 2: fused QKV projection. M=B*T rows, K=C, N=3*H.
// Each block: 64 rows, 4 waves x 16 rows. MFMA 16x16x32 bf16.
// q,k stored row-major [B*T][H]; v stored transposed vT[b][h][t].
// ---------------------------------------------------------------------------
__global__ __launch_bounds__(256) void proj_kernel(
    const float* __restrict__ x, const bf16_t* __restrict__ WT,
    bf16_t* __restrict__ qb, bf16_t* __restrict__ kb, bf16_t* __restrict__ vT) {
  const int lane = threadIdx.x & 63;
  const int wave = threadIdx.x >> 6;
  const int lr = lane & 15, lg = lane >> 4;
  const int m0 = blockIdx.x * 64 + wave * 16;
  const float* xrow = x + (size_t)(m0 + lr) * C;
  f32x4 acc[12];
#pragma unroll
  for (int i = 0; i < 12; ++i) acc[i] = f32x4{0.f, 0.f, 0.f, 0.f};
  for (int ks = 0; ks < C; ks += 32) {
    const int c0 = ks + lg * 8;
    f32x4 xa = *(const f32x4*)(xrow + c0);
    f32x4 xb = *(const f32x4*)(xrow + c0 + 4);
    bf16x8 af;
    af[0] = (bf16_t)xa[0]; af[1] = (bf16_t)xa[1];
    af[2] = (bf16_t)xa[2]; af[3] = (bf16_t)xa[3];
    af[4] = (bf16_t)xb[0]; af[5] = (bf16_t)xb[1];
    af[6] = (bf16_t)xb[2]; af[7] = (bf16_t)xb[3];
#pragma unroll
    for (int nt = 0; nt < 12; ++nt) {
      const bf16_t* wp =
          WT + (size_t)((nt >> 2) * H + (nt & 3) * 16 + lr) * C + c0;
      bf16x8 bfr = *(const bf16x8*)wp;
      acc[nt] = __builtin_amdgcn_mfma_f32_16x16x32_bf16(af, bfr, acc[nt], 0, 0, 0);
    }
  }
#pragma unroll
  for (int nt = 0; nt < 12; ++nt) {
    const int wsel = nt >> 2;
    const int h = (nt & 3) * 16 + lr;
#pragma unroll
    for (int r = 0; r < 4; ++r) {
      const int row = m0 + lg * 4 + r;  // global row in [0, B*T)
      bf16_t val = (bf16_t)acc[nt][r];
      if (wsel == 0)
        qb[(size_t)row * H + h] = val;
      else if (wsel == 1)
        kb[(size_t)row * H + h] = val;
      else
        vT[((size_t)(row >> 12) * H + h) * T + (row & (T - 1))] = val;
    }
  }
}

// ---------------------------------------------------------------------------
// Kernel 3: causal flash attention.
// Grid (T/64, B); 4 waves/block, each wave owns 16 q-rows. KV tile = 32.
// Q in registers; K and vT read from global (L2-resident, 2MB each).
// P routed through tiny wave-private LDS to build the PV A-fragment.
// ---------------------------------------------------------------------------
__global__ __launch_bounds__(256) void flash_kernel(
    const bf16_t* __restrict__ qb, const bf16_t* __restrict__ kb,
    const bf16_t* __restrict__ vT, float* __restrict__ out) {
  __shared__ __align__(16) bf16_t plds[4][16][40];  // stride 40 bf16 = 80B
  const int lane = threadIdx.x & 63;
  const int wave = threadIdx.x >> 6;
  const int lr = lane & 15, lg = lane >> 4;
  const int j = blockIdx.x, b = blockIdx.y;
  const int q0 = j * 64 + wave * 16;

  const bf16_t* qp = qb + (size_t)(b * T + q0 + lr) * H;
  const bf16x8 qf0 = *(const bf16x8*)(qp + lg * 8);
  const bf16x8 qf1 = *(const bf16x8*)(qp + 32 + lg * 8);
  const bf16_t* Kb = kb + (size_t)b * T * H;
  const bf16_t* Vb = vT + (size_t)b * H * T;

  f32x4 acc[4];
#pragma unroll
  for (int i = 0; i < 4; ++i) acc[i] = f32x4{0.f, 0.f, 0.f, 0.f};
  float m[4], l[4];
#pragma unroll
  for (int r = 0; r < 4; ++r) { m[r] = -1e30f; l[r] = 0.f; }

  const int nk = q0 + 16;  // causal: this wave needs keys [0, nk)
  for (int k0 = 0; k0 < nk; k0 += 32) {
    const bf16_t* kp0 = Kb + (size_t)(k0 + lr) * H + lg * 8;
    const bf16_t* kp1 = Kb + (size_t)(k0 + 16 + lr) * H + lg * 8;
    bf16x8 kf00 = *(const bf16x8*)(kp0);
    bf16x8 kf01 = *(const bf16x8*)(kp0 + 32);
    bf16x8 kf10 = *(const bf16x8*)(kp1);
    bf16x8 kf11 = *(const bf16x8*)(kp1 + 32);
    bf16x8 vf[4];
#pragma unroll
    for (int nt = 0; nt < 4; ++nt)
      vf[nt] = *(const bf16x8*)(Vb + (size_t)(nt * 16 + lr) * T + k0 + lg * 8);

    f32x4 z = f32x4{0.f, 0.f, 0.f, 0.f};
    f32x4 S0 = __builtin_amdgcn_mfma_f32_16x16x32_bf16(qf0, kf00, z, 0, 0, 0);
    S0 = __builtin_amdgcn_mfma_f32_16x16x32_bf16(qf1, kf01, S0, 0, 0, 0);
    f32x4 S1 = __builtin_amdgcn_mfma_f32_16x16x32_bf16(qf0, kf10, z, 0, 0, 0);
    S1 = __builtin_amdgcn_mfma_f32_16x16x32_bf16(qf1, kf11, S1, 0, 0, 0);

    if (k0 + 31 > q0) {  // wave-uniform: only diagonal-crossing tiles mask
#pragma unroll
      for (int r = 0; r < 4; ++r) {
        const int row = q0 + lg * 4 + r;
        S0[r] = (k0 + lr > row) ? -1e30f : S0[r];
        S1[r] = (k0 + 16 + lr > row) ? -1e30f : S1[r];
      }
    }

    float alpha[4];
#pragma unroll
    for (int r = 0; r < 4; ++r) {
      float t = fmaxf(S0[r], S1[r]);
      t = fmaxf(t, __shfl_xor(t, 1));
      t = fmaxf(t, __shfl_xor(t, 2));
      t = fmaxf(t, __shfl_xor(t, 4));
      t = fmaxf(t, __shfl_xor(t, 8));
      const float mn = fmaxf(m[r], t);
      alpha[r] = __expf(m[r] - mn);
      m[r] = mn;
      S0[r] = __expf(S0[r] - mn);
      S1[r] = __expf(S1[r] - mn);
      float rs = S0[r] + S1[r];
      rs += __shfl_xor(rs, 1);
      rs += __shfl_xor(rs, 2);
      rs += __shfl_xor(rs, 4);
      rs += __shfl_xor(rs, 8);
      l[r] = l[r] * alpha[r] + rs;
    }

    // P (D-layout) -> LDS -> A-fragment layout
#pragma unroll
    for (int r = 0; r < 4; ++r) {
      plds[wave][lg * 4 + r][lr] = (bf16_t)S0[r];
      plds[wave][lg * 4 + r][16 + lr] = (bf16_t)S1[r];
    }
    bf16x8 pf = *(const bf16x8*)(&plds[wave][lr][lg * 8]);

#pragma unroll
    for (int nt = 0; nt < 4; ++nt) {
#pragma unroll
      for (int r = 0; r < 4; ++r) acc[nt][r] *= alpha[r];
    }
#pragma unroll
    for (int nt = 0; nt < 4; ++nt)
      acc[nt] = __builtin_amdgcn_mfma_f32_16x16x32_bf16(pf, vf[nt], acc[nt], 0, 0, 0);
  }

  float inv[4];
#pragma unroll
  for (int r = 0; r < 4; ++r) inv[r] = 1.0f / l[r];
  float* op = out + (size_t)(b * T + q0 + lg * 4) * H;
#pragma unroll
  for (int nt = 0; nt < 4; ++nt) {
#pragma unroll
    for (int r = 0; r < 4; ++r)
      op[(size_t)r * H + nt * 16 + lr] = acc[nt][r] * inv[r];
  }
}

// ---------------------------------------------------------------------------
extern "C" void kernel_launch(void* const* d_in, const int* in_sizes, int n_in,
                              void* d_out, int out_size, void* d_ws,
                              size_t ws_size, hipStream_t stream) {
  const float* x = (const float*)d_in[0];
  const float* Wk = (const float*)d_in[1];
  const float* Wq = (const float*)d_in[2];
  const float* Wv = (const float*)d_in[3];
  float* out = (float*)d_out;
  char* ws = (char*)d_ws;
  const size_t SZ = (size_t)B * T * H * sizeof(bf16_t);  // 2 MB each
  bf16_t* qb = (bf16_t*)ws;
  bf16_t* kb = (bf16_t*)(ws + SZ);
  bf16_t* vT = (bf16_t*)(ws + 2 * SZ);
  bf16_t* WT = (bf16_t*)(ws + 3 * SZ);  // 384 KB

  wconv_kernel<<<(3 * H * C + 255) / 256, 256, 0, stream>>>(Wk, Wq, Wv, WT);
  proj_kernel<<<(B * T) / 64, 256, 0, stream>>>(x, WT, qb, kb, vT);
  flash_kernel<<<dim3(T / 64, B), 256, 0, stream>>>(qb, kb, vT, out);
}

// Round 2
// 157.389 us; speedup vs baseline: 1.3523x; 1.3523x over previous
//
#include <hip/hip_runtime.h>
#include <hip/hip_bf16.h>

typedef __bf16 bf16_t;
typedef __bf16 bf16x8 __attribute__((ext_vector_type(8)));
typedef float f32x4 __attribute__((ext_vector_type(4)));

constexpr int B = 4, T = 4096, C = 1024, H = 64;

// ---------------------------------------------------------------------------
// Kernel 1: weights -> bf16, transposed WT[w][h][c], w in {q,k,v}.
// 1/sqrt(H)=0.125 folded into Wq.
// ---------------------------------------------------------------------------
__global__ __launch_bounds__(256) void wconv_kernel(
    const float* __restrict__ Wk, const float* __restrict__ Wq,
    const float* __restrict__ Wv, bf16_t* __restrict__ WT) {
  int idx = blockIdx.x * 256 + threadIdx.x;
  if (idx >= 3 * H * C) return;
  int w = idx / (H * C);
  int rem = idx - w * H * C;
  int h = rem / C;
  int c = rem - h * C;
  const float* src = (w == 0) ? Wq : (w == 1) ? Wk : Wv;
  float f = src[c * H + h];
  if (w == 0) f *= 0.125f;
  WT[idx] = (bf16_t)f;
}

// ---------------------------------------------------------------------------
// Kernel 2: fused QKV projection, software-pipelined (double-buffered x & W).
// M=B*T, K=C, N=192. Block=64 rows, 4 waves x 16 rows, MFMA 16x16x32.
// q,k row-major [B*T][H]; v transposed vT[b][h][t].
// ---------------------------------------------------------------------------
__global__ __launch_bounds__(256, 1) void proj_kernel(
    const float* __restrict__ x, const bf16_t* __restrict__ WT,
    bf16_t* __restrict__ qb, bf16_t* __restrict__ kb, bf16_t* __restrict__ vT) {
  const int lane = threadIdx.x & 63;
  const int wave = threadIdx.x >> 6;
  const int lr = lane & 15, lg = lane >> 4;
  const int m0 = blockIdx.x * 64 + wave * 16;
  const float* xrow = x + (size_t)(m0 + lr) * C + lg * 8;
  const bf16_t* wrow[12];
#pragma unroll
  for (int nt = 0; nt < 12; ++nt)
    wrow[nt] = WT + (size_t)((nt >> 2) * H + (nt & 3) * 16 + lr) * C + lg * 8;

  f32x4 acc[12];
#pragma unroll
  for (int i = 0; i < 12; ++i) acc[i] = f32x4{0.f, 0.f, 0.f, 0.f};

  f32x4 xa = *(const f32x4*)(xrow);
  f32x4 xb = *(const f32x4*)(xrow + 4);
  bf16x8 wf[12];
#pragma unroll
  for (int nt = 0; nt < 12; ++nt) wf[nt] = *(const bf16x8*)(wrow[nt]);

  int ks = 0;
  while (true) {
    const bool last = (ks + 32 >= C);
    f32x4 nxa, nxb;
    bf16x8 nwf[12];
    if (!last) {  // prefetch next K-step while current MFMAs run
      nxa = *(const f32x4*)(xrow + ks + 32);
      nxb = *(const f32x4*)(xrow + ks + 36);
#pragma unroll
      for (int nt = 0; nt < 12; ++nt)
        nwf[nt] = *(const bf16x8*)(wrow[nt] + ks + 32);
    }
    bf16x8 af;
    af[0] = (bf16_t)xa[0]; af[1] = (bf16_t)xa[1];
    af[2] = (bf16_t)xa[2]; af[3] = (bf16_t)xa[3];
    af[4] = (bf16_t)xb[0]; af[5] = (bf16_t)xb[1];
    af[6] = (bf16_t)xb[2]; af[7] = (bf16_t)xb[3];
#pragma unroll
    for (int nt = 0; nt < 12; ++nt)
      acc[nt] = __builtin_amdgcn_mfma_f32_16x16x32_bf16(af, wf[nt], acc[nt], 0, 0, 0);
    if (last) break;
    xa = nxa; xb = nxb;
#pragma unroll
    for (int nt = 0; nt < 12; ++nt) wf[nt] = nwf[nt];
    ks += 32;
  }

#pragma unroll
  for (int nt = 0; nt < 12; ++nt) {
    const int wsel = nt >> 2;
    const int h = (nt & 3) * 16 + lr;
#pragma unroll
    for (int r = 0; r < 4; ++r) {
      const int row = m0 + lg * 4 + r;
      bf16_t val = (bf16_t)acc[nt][r];
      if (wsel == 0)
        qb[(size_t)row * H + h] = val;
      else if (wsel == 1)
        kb[(size_t)row * H + h] = val;
      else
        vT[((size_t)(row >> 12) * H + h) * T + (row & (T - 1))] = val;
    }
  }
}

// ---------------------------------------------------------------------------
// Kernel 3: causal flash attention, KV-parallel waves.
// Block = 16 q-rows; 4 waves each process 64-key chunks strided by 256
// (online softmax is order-free), then combine (m,l,acc) via LDS.
// Grid = B*T/16 = 1024 blocks -> 4 blocks/CU, 16 waves/CU.
// ---------------------------------------------------------------------------
__global__ __launch_bounds__(256, 4) void flash_kernel(
    const bf16_t* __restrict__ qb, const bf16_t* __restrict__ kb,
    const bf16_t* __restrict__ vT, float* __restrict__ out) {
  __shared__ union {
    __align__(16) bf16_t p[4][16][72];  // per-wave P round-trip, stride 144B
    struct {
      float acc[4][64][20];  // [wave][lane][nt*4+r], padded
      float ml[4][64][8];    // [wave][lane][m0..3, l0..3]
    } red;
  } sm;

  const int lane = threadIdx.x & 63;
  const int wave = threadIdx.x >> 6;
  const int lr = lane & 15, lg = lane >> 4;
  const int i = blockIdx.x;
  const int qg_lin = i >> 2;
  const int b = i & 3;
  // pair short/long q-tiles so each CU's blocks are balanced
  const int qg = (qg_lin & 1) ? (255 - (qg_lin >> 1)) : (qg_lin >> 1);
  const int q0 = qg * 16;

  const bf16_t* qp = qb + (size_t)(b * T + q0 + lr) * H;
  const bf16x8 qf0 = *(const bf16x8*)(qp + lg * 8);
  const bf16x8 qf1 = *(const bf16x8*)(qp + 32 + lg * 8);
  const bf16_t* Kb = kb + (size_t)b * T * H;
  const bf16_t* Vb = vT + (size_t)b * H * T;

  f32x4 acc[4];
#pragma unroll
  for (int t = 0; t < 4; ++t) acc[t] = f32x4{0.f, 0.f, 0.f, 0.f};
  float m[4], l[4];
#pragma unroll
  for (int r = 0; r < 4; ++r) { m[r] = -1e30f; l[r] = 0.f; }

  const int nk = q0 + 16;  // causal bound for this 16-row group
  for (int k0 = wave * 64; k0 < nk; k0 += 256) {
    // ---- load K fragments (4 sub-tiles of 16 keys x K=64 contraction)
    bf16x8 kf[4][2];
#pragma unroll
    for (int st = 0; st < 4; ++st) {
      const bf16_t* kp = Kb + (size_t)(k0 + st * 16 + lr) * H + lg * 8;
      kf[st][0] = *(const bf16x8*)(kp);
      kf[st][1] = *(const bf16x8*)(kp + 32);
    }
    // ---- load V fragments (B-operand of PV: Vt rows = out cols)
    bf16x8 vf[4][2];
#pragma unroll
    for (int nt = 0; nt < 4; ++nt) {
      const bf16_t* vp = Vb + (size_t)(nt * 16 + lr) * T + k0 + lg * 8;
      vf[nt][0] = *(const bf16x8*)(vp);
      vf[nt][1] = *(const bf16x8*)(vp + 32);
    }
    // ---- S = q @ k^T  (4 tiles of 16 keys)
    const f32x4 z = f32x4{0.f, 0.f, 0.f, 0.f};
    f32x4 S[4];
#pragma unroll
    for (int st = 0; st < 4; ++st) {
      S[st] = __builtin_amdgcn_mfma_f32_16x16x32_bf16(qf0, kf[st][0], z, 0, 0, 0);
      S[st] = __builtin_amdgcn_mfma_f32_16x16x32_bf16(qf1, kf[st][1], S[st], 0, 0, 0);
    }
    // ---- causal mask (only diagonal-crossing chunks; wave-uniform branch)
    if (k0 + 63 > q0) {
#pragma unroll
      for (int st = 0; st < 4; ++st)
#pragma unroll
        for (int r = 0; r < 4; ++r) {
          const int row = q0 + lg * 4 + r;
          S[st][r] = (k0 + st * 16 + lr > row) ? -1e30f : S[st][r];
        }
    }
    // ---- online softmax over the 64-key chunk
    float alpha[4];
#pragma unroll
    for (int r = 0; r < 4; ++r) {
      float t = fmaxf(fmaxf(S[0][r], S[1][r]), fmaxf(S[2][r], S[3][r]));
      t = fmaxf(t, __shfl_xor(t, 1));
      t = fmaxf(t, __shfl_xor(t, 2));
      t = fmaxf(t, __shfl_xor(t, 4));
      t = fmaxf(t, __shfl_xor(t, 8));
      const float mn = fmaxf(m[r], t);
      alpha[r] = __expf(m[r] - mn);
      m[r] = mn;
#pragma unroll
      for (int st = 0; st < 4; ++st) S[st][r] = __expf(S[st][r] - mn);
      float rs = (S[0][r] + S[1][r]) + (S[2][r] + S[3][r]);
      rs += __shfl_xor(rs, 1);
      rs += __shfl_xor(rs, 2);
      rs += __shfl_xor(rs, 4);
      rs += __shfl_xor(rs, 8);
      l[r] = l[r] * alpha[r] + rs;
    }
    // ---- P (D-layout) -> LDS -> A-fragment layout
#pragma unroll
    for (int st = 0; st < 4; ++st)
#pragma unroll
      for (int r = 0; r < 4; ++r)
        sm.p[wave][lg * 4 + r][st * 16 + lr] = (bf16_t)S[st][r];
    const bf16x8 pf0 = *(const bf16x8*)(&sm.p[wave][lr][lg * 8]);
    const bf16x8 pf1 = *(const bf16x8*)(&sm.p[wave][lr][32 + lg * 8]);
    // ---- rescale + PV
#pragma unroll
    for (int nt = 0; nt < 4; ++nt)
#pragma unroll
      for (int r = 0; r < 4; ++r) acc[nt][r] *= alpha[r];
#pragma unroll
    for (int nt = 0; nt < 4; ++nt) {
      acc[nt] = __builtin_amdgcn_mfma_f32_16x16x32_bf16(pf0, vf[nt][0], acc[nt], 0, 0, 0);
      acc[nt] = __builtin_amdgcn_mfma_f32_16x16x32_bf16(pf1, vf[nt][1], acc[nt], 0, 0, 0);
    }
  }

  // ---- cross-wave combine of (m, l, acc)
  __syncthreads();  // p[] no longer needed by any wave
#pragma unroll
  for (int nt = 0; nt < 4; ++nt)
    *(f32x4*)(&sm.red.acc[wave][lane][nt * 4]) = acc[nt];
#pragma unroll
  for (int r = 0; r < 4; ++r) {
    sm.red.ml[wave][lane][r] = m[r];
    sm.red.ml[wave][lane][4 + r] = l[r];
  }
  __syncthreads();

  // wave w produces output columns [w*16, w*16+16)
#pragma unroll
  for (int r = 0; r < 4; ++r) {
    float m0 = sm.red.ml[0][lane][r], m1 = sm.red.ml[1][lane][r];
    float m2 = sm.red.ml[2][lane][r], m3 = sm.red.ml[3][lane][r];
    float M = fmaxf(fmaxf(m0, m1), fmaxf(m2, m3));
    float e0 = __expf(m0 - M), e1 = __expf(m1 - M);
    float e2 = __expf(m2 - M), e3 = __expf(m3 - M);
    float L = e0 * sm.red.ml[0][lane][4 + r] + e1 * sm.red.ml[1][lane][4 + r] +
              e2 * sm.red.ml[2][lane][4 + r] + e3 * sm.red.ml[3][lane][4 + r];
    float o = e0 * sm.red.acc[0][lane][wave * 4 + r] +
              e1 * sm.red.acc[1][lane][wave * 4 + r] +
              e2 * sm.red.acc[2][lane][wave * 4 + r] +
              e3 * sm.red.acc[3][lane][wave * 4 + r];
    out[(size_t)(b * T + q0 + lg * 4 + r) * H + wave * 16 + lr] = o / L;
  }
}

// ---------------------------------------------------------------------------
extern "C" void kernel_launch(void* const* d_in, const int* in_sizes, int n_in,
                              void* d_out, int out_size, void* d_ws,
                              size_t ws_size, hipStream_t stream) {
  const float* x = (const float*)d_in[0];
  const float* Wk = (const float*)d_in[1];
  const float* Wq = (const float*)d_in[2];
  const float* Wv = (const float*)d_in[3];
  float* out = (float*)d_out;
  char* ws = (char*)d_ws;
  const size_t SZ = (size_t)B * T * H * sizeof(bf16_t);  // 2 MB each
  bf16_t* qb = (bf16_t*)ws;
  bf16_t* kb = (bf16_t*)(ws + SZ);
  bf16_t* vT = (bf16_t*)(ws + 2 * SZ);
  bf16_t* WT = (bf16_t*)(ws + 3 * SZ);  // 384 KB

  wconv_kernel<<<(3 * H * C + 255) / 256, 256, 0, stream>>>(Wk, Wq, Wv, WT);
  proj_kernel<<<(B * T) / 64, 256, 0, stream>>>(x, WT, qb, kb, vT);
  flash_kernel<<<dim3(B * T / 16), 256, 0, stream>>>(qb, kb, vT, out);
}

// Round 3
// 146.628 us; speedup vs baseline: 1.4515x; 1.0734x over previous
//
#include <hip/hip_runtime.h>
#include <hip/hip_bf16.h>

typedef __bf16 bf16_t;
typedef __bf16 bf16x4 __attribute__((ext_vector_type(4)));
typedef __bf16 bf16x8 __attribute__((ext_vector_type(8)));
typedef float f32x4 __attribute__((ext_vector_type(4)));

constexpr int B = 4, T = 4096, C = 1024, H = 64;

// ---------------------------------------------------------------------------
// Kernel 1: weights -> bf16, transposed WT[w][h][c], w in {q,k,v}.
// 1/sqrt(H)=0.125 folded into Wq.
// ---------------------------------------------------------------------------
__global__ __launch_bounds__(256) void wconv_kernel(
    const float* __restrict__ Wk, const float* __restrict__ Wq,
    const float* __restrict__ Wv, bf16_t* __restrict__ WT) {
  int idx = blockIdx.x * 256 + threadIdx.x;
  if (idx >= 3 * H * C) return;
  int w = idx / (H * C);
  int rem = idx - w * H * C;
  int h = rem / C;
  int c = rem - h * C;
  const float* src = (w == 0) ? Wq : (w == 1) ? Wk : Wv;
  float f = src[c * H + h];
  if (w == 0) f *= 0.125f;
  WT[idx] = (bf16_t)f;
}

// ---------------------------------------------------------------------------
// Kernel 2: fused QKV projection. Block = 16 rows; 4 waves split the 12
// output 16-col tiles (3 each). Grid = M/16 = 1024 -> 4 blocks/CU.
// Double-buffered K-loop. q,k row-major; v transposed vT[b][h][t].
// ---------------------------------------------------------------------------
__global__ __launch_bounds__(256, 4) void proj_kernel(
    const float* __restrict__ x, const bf16_t* __restrict__ WT,
    bf16_t* __restrict__ qb, bf16_t* __restrict__ kb, bf16_t* __restrict__ vT) {
  const int lane = threadIdx.x & 63;
  const int wave = threadIdx.x >> 6;
  const int lr = lane & 15, lg = lane >> 4;
  const int m0 = blockIdx.x * 16;
  const float* xrow = x + (size_t)(m0 + lr) * C + lg * 8;
  const bf16_t* wrow[3];
#pragma unroll
  for (int t = 0; t < 3; ++t) {
    const int nt = wave * 3 + t;
    wrow[t] = WT + (size_t)((nt >> 2) * H + (nt & 3) * 16 + lr) * C + lg * 8;
  }
  f32x4 acc[3];
#pragma unroll
  for (int t = 0; t < 3; ++t) acc[t] = f32x4{0.f, 0.f, 0.f, 0.f};

  f32x4 xa = *(const f32x4*)(xrow);
  f32x4 xb = *(const f32x4*)(xrow + 4);
  bf16x8 wf[3];
#pragma unroll
  for (int t = 0; t < 3; ++t) wf[t] = *(const bf16x8*)(wrow[t]);

  int ks = 0;
  while (true) {
    const bool last = (ks + 32 >= C);
    f32x4 nxa, nxb;
    bf16x8 nwf[3];
    if (!last) {  // prefetch next K-step
      nxa = *(const f32x4*)(xrow + ks + 32);
      nxb = *(const f32x4*)(xrow + ks + 36);
#pragma unroll
      for (int t = 0; t < 3; ++t) nwf[t] = *(const bf16x8*)(wrow[t] + ks + 32);
    }
    bf16x8 af;
    af[0] = (bf16_t)xa[0]; af[1] = (bf16_t)xa[1];
    af[2] = (bf16_t)xa[2]; af[3] = (bf16_t)xa[3];
    af[4] = (bf16_t)xb[0]; af[5] = (bf16_t)xb[1];
    af[6] = (bf16_t)xb[2]; af[7] = (bf16_t)xb[3];
#pragma unroll
    for (int t = 0; t < 3; ++t)
      acc[t] = __builtin_amdgcn_mfma_f32_16x16x32_bf16(af, wf[t], acc[t], 0, 0, 0);
    if (last) break;
    xa = nxa; xb = nxb;
#pragma unroll
    for (int t = 0; t < 3; ++t) wf[t] = nwf[t];
    ks += 32;
  }

#pragma unroll
  for (int t = 0; t < 3; ++t) {
    const int nt = wave * 3 + t;
    const int wsel = nt >> 2;
    const int h = (nt & 3) * 16 + lr;
#pragma unroll
    for (int r = 0; r < 4; ++r) {
      const int row = m0 + lg * 4 + r;
      bf16_t val = (bf16_t)acc[t][r];
      if (wsel == 0)
        qb[(size_t)row * H + h] = val;
      else if (wsel == 1)
        kb[(size_t)row * H + h] = val;
      else
        vT[((size_t)(row >> 12) * H + h) * T + (row & (T - 1))] = val;
    }
  }
}

// ---------------------------------------------------------------------------
// Kernel 3: causal flash attention, balanced pairs.
// Block = 512 threads (8 waves), processes q-tiles (128+j) then (127-j):
// constant work per block. Each wave takes 64-key chunks strided by 512.
// Swapped QK MFMA (S[k][q]) -> per-lane scalar softmax, 2 shfls per reduce.
// ---------------------------------------------------------------------------
__global__ __launch_bounds__(512, 4) void flash_kernel(
    const bf16_t* __restrict__ qb, const bf16_t* __restrict__ kb,
    const bf16_t* __restrict__ vT, float* __restrict__ out) {
  __shared__ __align__(16) bf16_t plds[8][16][72];   // P round-trip, per wave
  __shared__ __align__(16) float red_acc[8][64][20]; // [wave][lane][nt*4+r]
  __shared__ float red_ml[8][16][2];                 // [wave][q-row][m,l]

  const int lane = threadIdx.x & 63;
  const int wave = threadIdx.x >> 6;
  const int lr = lane & 15, lg = lane >> 4;
  const int i = blockIdx.x;
  const int j = i >> 2;
  const int b = i & 3;
  const bf16_t* Kb = kb + (size_t)b * T * H;
  const bf16_t* Vb = vT + (size_t)b * H * T;

  for (int phase = 0; phase < 2; ++phase) {
    const int qg = phase ? (127 - j) : (128 + j);
    const int q0 = qg * 16;
    const bf16_t* qp = qb + (size_t)(b * T + q0 + lr) * H;
    const bf16x8 qf0 = *(const bf16x8*)(qp + lg * 8);
    const bf16x8 qf1 = *(const bf16x8*)(qp + 32 + lg * 8);

    f32x4 acc[4];
#pragma unroll
    for (int t = 0; t < 4; ++t) acc[t] = f32x4{0.f, 0.f, 0.f, 0.f};
    float m = -1e30f, l = 0.f;

    const int nk = q0 + 16;
    for (int k0 = wave * 64; k0 < nk; k0 += 512) {
      bf16x8 kf[4][2];
#pragma unroll
      for (int st = 0; st < 4; ++st) {
        const bf16_t* kp = Kb + (size_t)(k0 + st * 16 + lr) * H + lg * 8;
        kf[st][0] = *(const bf16x8*)(kp);
        kf[st][1] = *(const bf16x8*)(kp + 32);
      }
      // S[k][q]: swapped operands -> lane owns 16 scores of q-row (q0+lr)
      const f32x4 z = f32x4{0.f, 0.f, 0.f, 0.f};
      f32x4 S[4];
#pragma unroll
      for (int st = 0; st < 4; ++st) {
        S[st] = __builtin_amdgcn_mfma_f32_16x16x32_bf16(kf[st][0], qf0, z, 0, 0, 0);
        S[st] = __builtin_amdgcn_mfma_f32_16x16x32_bf16(kf[st][1], qf1, S[st], 0, 0, 0);
      }
      // V fragments issued here; latency hides under softmax VALU
      bf16x8 vf[4][2];
#pragma unroll
      for (int nt = 0; nt < 4; ++nt) {
        const bf16_t* vp = Vb + (size_t)(nt * 16 + lr) * T + k0 + lg * 8;
        vf[nt][0] = *(const bf16x8*)(vp);
        vf[nt][1] = *(const bf16x8*)(vp + 32);
      }
      if (k0 + 63 > q0) {  // causal mask, diagonal chunks only
#pragma unroll
        for (int st = 0; st < 4; ++st)
#pragma unroll
          for (int r = 0; r < 4; ++r)
            S[st][r] = (k0 + st * 16 + lg * 4 + r > q0 + lr) ? -1e30f : S[st][r];
      }
      // per-lane softmax for q-row (q0+lr); reduce across lg groups: 2 shfls
      float t01 = fmaxf(fmaxf(S[0][0], S[0][1]), fmaxf(S[0][2], S[0][3]));
      float t23 = fmaxf(fmaxf(S[1][0], S[1][1]), fmaxf(S[1][2], S[1][3]));
      float t45 = fmaxf(fmaxf(S[2][0], S[2][1]), fmaxf(S[2][2], S[2][3]));
      float t67 = fmaxf(fmaxf(S[3][0], S[3][1]), fmaxf(S[3][2], S[3][3]));
      float t = fmaxf(fmaxf(t01, t23), fmaxf(t45, t67));
      t = fmaxf(t, __shfl_xor(t, 16));
      t = fmaxf(t, __shfl_xor(t, 32));
      const float mn = fmaxf(m, t);
      const float alpha = __expf(m - mn);
      m = mn;
      float rs = 0.f;
#pragma unroll
      for (int st = 0; st < 4; ++st)
#pragma unroll
        for (int r = 0; r < 4; ++r) {
          S[st][r] = __expf(S[st][r] - mn);
          rs += S[st][r];
        }
      rs += __shfl_xor(rs, 16);
      rs += __shfl_xor(rs, 32);
      l = l * alpha + rs;
      // P -> LDS (packed b64), read back as PV A-fragment
#pragma unroll
      for (int st = 0; st < 4; ++st) {
        bf16x4 pk;
        pk[0] = (bf16_t)S[st][0]; pk[1] = (bf16_t)S[st][1];
        pk[2] = (bf16_t)S[st][2]; pk[3] = (bf16_t)S[st][3];
        *(bf16x4*)(&plds[wave][lr][st * 16 + lg * 4]) = pk;
      }
      const bf16x8 pf0 = *(const bf16x8*)(&plds[wave][lr][lg * 8]);
      const bf16x8 pf1 = *(const bf16x8*)(&plds[wave][lr][32 + lg * 8]);
      // rescale acc rows (alpha lives at lane lg*4+r) and PV
#pragma unroll
      for (int r = 0; r < 4; ++r) {
        const float ar = __shfl(alpha, lg * 4 + r);
#pragma unroll
        for (int nt = 0; nt < 4; ++nt) acc[nt][r] *= ar;
      }
#pragma unroll
      for (int nt = 0; nt < 4; ++nt) {
        acc[nt] = __builtin_amdgcn_mfma_f32_16x16x32_bf16(pf0, vf[nt][0], acc[nt], 0, 0, 0);
        acc[nt] = __builtin_amdgcn_mfma_f32_16x16x32_bf16(pf1, vf[nt][1], acc[nt], 0, 0, 0);
      }
    }

    // ---- combine partials across the 8 waves
    __syncthreads();  // previous phase's combine fully done; plds quiet
#pragma unroll
    for (int nt = 0; nt < 4; ++nt)
      *(f32x4*)(&red_acc[wave][lane][nt * 4]) = acc[nt];
    if (lg == 0) {
      red_ml[wave][lr][0] = m;
      red_ml[wave][lr][1] = l;
    }
    __syncthreads();

    if (wave < 4) {  // wave w -> output columns [w*16, w*16+16)
#pragma unroll
      for (int r = 0; r < 4; ++r) {
        const int row = lg * 4 + r;
        float mw[8];
#pragma unroll
        for (int w2 = 0; w2 < 8; ++w2) mw[w2] = red_ml[w2][row][0];
        float M = fmaxf(fmaxf(fmaxf(mw[0], mw[1]), fmaxf(mw[2], mw[3])),
                        fmaxf(fmaxf(mw[4], mw[5]), fmaxf(mw[6], mw[7])));
        float L = 0.f, o = 0.f;
#pragma unroll
        for (int w2 = 0; w2 < 8; ++w2) {
          const float e = __expf(mw[w2] - M);
          L += e * red_ml[w2][row][1];
          o += e * red_acc[w2][lane][wave * 4 + r];
        }
        out[(size_t)(b * T + q0 + row) * H + wave * 16 + lr] = o / L;
      }
    }
  }
}

// ---------------------------------------------------------------------------
extern "C" void kernel_launch(void* const* d_in, const int* in_sizes, int n_in,
                              void* d_out, int out_size, void* d_ws,
                              size_t ws_size, hipStream_t stream) {
  const float* x = (const float*)d_in[0];
  const float* Wk = (const float*)d_in[1];
  const float* Wq = (const float*)d_in[2];
  const float* Wv = (const float*)d_in[3];
  float* out = (float*)d_out;
  char* ws = (char*)d_ws;
  const size_t SZ = (size_t)B * T * H * sizeof(bf16_t);  // 2 MB each
  bf16_t* qb = (bf16_t*)ws;
  bf16_t* kb = (bf16_t*)(ws + SZ);
  bf16_t* vT = (bf16_t*)(ws + 2 * SZ);
  bf16_t* WT = (bf16_t*)(ws + 3 * SZ);  // 384 KB

  wconv_kernel<<<(3 * H * C + 255) / 256, 256, 0, stream>>>(Wk, Wq, Wv, WT);
  proj_kernel<<<(B * T) / 16, 256, 0, stream>>>(x, WT, qb, kb, vT);
  flash_kernel<<<dim3(B * T / 32), 512, 0, stream>>>(qb, kb, vT, out);
}

// Round 4
// 102.666 us; speedup vs baseline: 2.0731x; 1.4282x over previous
//
#include <hip/hip_runtime.h>
#include <hip/hip_bf16.h>

typedef __bf16 bf16_t;
typedef __bf16 bf16x4 __attribute__((ext_vector_type(4)));
typedef __bf16 bf16x8 __attribute__((ext_vector_type(8)));
typedef float f32x4 __attribute__((ext_vector_type(4)));

constexpr int B = 4, T = 4096, C = 1024, H = 64;

__device__ __forceinline__ void gll16(const void* g, void* l) {
  __builtin_amdgcn_global_load_lds(
      (const __attribute__((address_space(1))) void*)g,
      (__attribute__((address_space(3))) void*)l, 16, 0, 0);
}

// ---------------------------------------------------------------------------
// Kernel 1: weights -> bf16, transposed WT[w][h][c], w in {q,k,v}.
// 1/sqrt(H)=0.125 folded into Wq.
// ---------------------------------------------------------------------------
__global__ __launch_bounds__(256) void wconv_kernel(
    const float* __restrict__ Wk, const float* __restrict__ Wq,
    const float* __restrict__ Wv, bf16_t* __restrict__ WT) {
  int idx = blockIdx.x * 256 + threadIdx.x;
  if (idx >= 3 * H * C) return;
  int w = idx / (H * C);
  int rem = idx - w * H * C;
  int h = rem / C;
  int c = rem - h * C;
  const float* src = (w == 0) ? Wq : (w == 1) ? Wk : Wv;
  float f = src[c * H + h];
  if (w == 0) f *= 0.125f;
  WT[idx] = (bf16_t)f;
}

// ---------------------------------------------------------------------------
// Kernel 2: fused QKV projection, LDS-staged 2-phase pipeline (T3-minimum).
// Block: 64 rows x 192 cols, BK=64. 4 waves, each 16 rows x 12 nt tiles.
// x (f32) and WT (bf16) staged via global_load_lds(16B) with XOR swizzle
// ((row&7)<<4) applied on the GLOBAL source address (linear LDS dest) and
// again on the LDS read -> conflict-free ds_read_b128 fragments.
// ---------------------------------------------------------------------------
__global__ __launch_bounds__(256, 2) void proj_kernel(
    const float* __restrict__ x, const bf16_t* __restrict__ WT,
    bf16_t* __restrict__ qb, bf16_t* __restrict__ kb, bf16_t* __restrict__ vT) {
  __shared__ __align__(16) char xsm[2][16384];  // [64 rows][64 f32] swizzled
  __shared__ __align__(16) char wsm[2][24576];  // [192 rows][64 bf16] swizzled
  const int lane = threadIdx.x & 63;
  const int wave = threadIdx.x >> 6;
  const int lr = lane & 15, lg = lane >> 4;
  const int m0 = blockIdx.x * 64;
  const int w16 = wave * 16;

  // staging address components (per-thread constants)
  const int xrow_s = w16 + (lane >> 4);        // + c*4
  const int xcbl = (lane & 15) * 16;
  const int wrow_s = wave * 48 + (lane >> 3);  // + c*8
  const int wcbl = (lane & 7) * 16;

  f32x4 acc[12];
#pragma unroll
  for (int i = 0; i < 12; ++i) acc[i] = f32x4{0.f, 0.f, 0.f, 0.f};

  auto stage = [&](int buf, int ks) {
#pragma unroll
    for (int c = 0; c < 4; ++c) {  // x tile: 64 rows x 256B
      const int row = xrow_s + c * 4;
      const int scb = xcbl ^ ((row & 7) << 4);
      const float* g = x + (size_t)(m0 + row) * C + ks + (scb >> 2);
      gll16(g, &xsm[buf][wave * 4096 + c * 1024 + lane * 16]);
    }
#pragma unroll
    for (int c = 0; c < 6; ++c) {  // W tile: 192 rows x 128B
      const int row = wrow_s + c * 8;
      const int scb = wcbl ^ ((row & 7) << 4);
      const bf16_t* g = WT + (size_t)row * C + ks + (scb >> 1);
      gll16(g, &wsm[buf][wave * 6144 + c * 1024 + lane * 16]);
    }
  };

  stage(0, 0);
  __syncthreads();
  for (int t = 0; t < 16; ++t) {
    const int cur = t & 1;
    if (t < 15) stage(cur ^ 1, (t + 1) * 64);  // issue next-tile loads first
    const char* xb_ = xsm[cur];
    const char* wb_ = wsm[cur];
#pragma unroll
    for (int ksub = 0; ksub < 2; ++ksub) {
      const int xrow = w16 + lr;
      const int xsw = (xrow & 7) << 4;
      const int cb = ksub * 128 + lg * 32;
      const f32x4 xa = *(const f32x4*)(xb_ + xrow * 256 + (cb ^ xsw));
      const f32x4 xv = *(const f32x4*)(xb_ + xrow * 256 + ((cb + 16) ^ xsw));
      bf16x8 af;
      af[0] = (bf16_t)xa[0]; af[1] = (bf16_t)xa[1];
      af[2] = (bf16_t)xa[2]; af[3] = (bf16_t)xa[3];
      af[4] = (bf16_t)xv[0]; af[5] = (bf16_t)xv[1];
      af[6] = (bf16_t)xv[2]; af[7] = (bf16_t)xv[3];
#pragma unroll
      for (int nt = 0; nt < 12; ++nt) {
        const int wrow = nt * 16 + lr;
        const int wby =
            wrow * 128 + ((ksub * 64 + lg * 16) ^ ((wrow & 7) << 4));
        const bf16x8 wf = *(const bf16x8*)(wb_ + wby);
        acc[nt] = __builtin_amdgcn_mfma_f32_16x16x32_bf16(af, wf, acc[nt], 0, 0, 0);
      }
    }
    __syncthreads();
  }

#pragma unroll
  for (int nt = 0; nt < 12; ++nt) {
    const int wsel = nt >> 2;
    const int h = (nt & 3) * 16 + lr;
#pragma unroll
    for (int r = 0; r < 4; ++r) {
      const int row = m0 + w16 + lg * 4 + r;
      bf16_t val = (bf16_t)acc[nt][r];
      if (wsel == 0)
        qb[(size_t)row * H + h] = val;
      else if (wsel == 1)
        kb[(size_t)row * H + h] = val;
      else
        vT[((size_t)(row >> 12) * H + h) * T + (row & (T - 1))] = val;
    }
  }
}

// ---------------------------------------------------------------------------
// Kernel 3: causal flash attention, balanced pairs, fully swapped MFMAs.
// QK: mfma(K,Q) -> S[k][q], lane owns q-row lr -> scalar softmax (2 shfls).
// PV: mfma(V,P) -> acc col=q=lr -> per-lane alpha rescale (no shfl),
// contiguous f32x4 stores.
// ---------------------------------------------------------------------------
__global__ __launch_bounds__(512, 4) void flash_kernel(
    const bf16_t* __restrict__ qb, const bf16_t* __restrict__ kb,
    const bf16_t* __restrict__ vT, float* __restrict__ out) {
  __shared__ __align__(16) bf16_t plds[8][16][72];   // P round-trip, per wave
  __shared__ __align__(16) float red_acc[8][64][20]; // [wave][lane][nt*4+r]
  __shared__ float red_ml[8][16][2];                 // [wave][q-row][m,l]

  const int lane = threadIdx.x & 63;
  const int wave = threadIdx.x >> 6;
  const int lr = lane & 15, lg = lane >> 4;
  const int i = blockIdx.x;
  const int j = i >> 2;
  const int b = i & 3;
  const bf16_t* Kb = kb + (size_t)b * T * H;
  const bf16_t* Vb = vT + (size_t)b * H * T;

  for (int phase = 0; phase < 2; ++phase) {
    const int qg = phase ? (127 - j) : (128 + j);
    const int q0 = qg * 16;
    const bf16_t* qp = qb + (size_t)(b * T + q0 + lr) * H;
    const bf16x8 qf0 = *(const bf16x8*)(qp + lg * 8);
    const bf16x8 qf1 = *(const bf16x8*)(qp + 32 + lg * 8);

    f32x4 acc[4];
#pragma unroll
    for (int t = 0; t < 4; ++t) acc[t] = f32x4{0.f, 0.f, 0.f, 0.f};
    float m = -1e30f, l = 0.f;

    const int nk = q0 + 16;
    for (int k0 = wave * 64; k0 < nk; k0 += 512) {
      bf16x8 kf[4][2];
#pragma unroll
      for (int st = 0; st < 4; ++st) {
        const bf16_t* kp = Kb + (size_t)(k0 + st * 16 + lr) * H + lg * 8;
        kf[st][0] = *(const bf16x8*)(kp);
        kf[st][1] = *(const bf16x8*)(kp + 32);
      }
      const f32x4 z = f32x4{0.f, 0.f, 0.f, 0.f};
      f32x4 S[4];
#pragma unroll
      for (int st = 0; st < 4; ++st) {
        S[st] = __builtin_amdgcn_mfma_f32_16x16x32_bf16(kf[st][0], qf0, z, 0, 0, 0);
        S[st] = __builtin_amdgcn_mfma_f32_16x16x32_bf16(kf[st][1], qf1, S[st], 0, 0, 0);
      }
      bf16x8 vf[4][2];
#pragma unroll
      for (int nt = 0; nt < 4; ++nt) {
        const bf16_t* vp = Vb + (size_t)(nt * 16 + lr) * T + k0 + lg * 8;
        vf[nt][0] = *(const bf16x8*)(vp);
        vf[nt][1] = *(const bf16x8*)(vp + 32);
      }
      if (k0 + 63 > q0) {  // causal mask, diagonal chunks only
#pragma unroll
        for (int st = 0; st < 4; ++st)
#pragma unroll
          for (int r = 0; r < 4; ++r)
            S[st][r] = (k0 + st * 16 + lg * 4 + r > q0 + lr) ? -1e30f : S[st][r];
      }
      // per-lane softmax for q-row (q0+lr); 2 shfls per reduce
      float t01 = fmaxf(fmaxf(S[0][0], S[0][1]), fmaxf(S[0][2], S[0][3]));
      float t23 = fmaxf(fmaxf(S[1][0], S[1][1]), fmaxf(S[1][2], S[1][3]));
      float t45 = fmaxf(fmaxf(S[2][0], S[2][1]), fmaxf(S[2][2], S[2][3]));
      float t67 = fmaxf(fmaxf(S[3][0], S[3][1]), fmaxf(S[3][2], S[3][3]));
      float t = fmaxf(fmaxf(t01, t23), fmaxf(t45, t67));
      t = fmaxf(t, __shfl_xor(t, 16));
      t = fmaxf(t, __shfl_xor(t, 32));
      const float mn = fmaxf(m, t);
      const float alpha = __expf(m - mn);
      m = mn;
      float rs = 0.f;
#pragma unroll
      for (int st = 0; st < 4; ++st)
#pragma unroll
        for (int r = 0; r < 4; ++r) {
          S[st][r] = __expf(S[st][r] - mn);
          rs += S[st][r];
        }
      rs += __shfl_xor(rs, 16);
      rs += __shfl_xor(rs, 32);
      l = l * alpha + rs;
      // P -> LDS (packed b64) -> B-fragment (identical lane map to old A-frag)
#pragma unroll
      for (int st = 0; st < 4; ++st) {
        bf16x4 pk;
        pk[0] = (bf16_t)S[st][0]; pk[1] = (bf16_t)S[st][1];
        pk[2] = (bf16_t)S[st][2]; pk[3] = (bf16_t)S[st][3];
        *(bf16x4*)(&plds[wave][lr][st * 16 + lg * 4]) = pk;
      }
      // rescale (per-lane scalar now: acc col = q = lr)
#pragma unroll
      for (int nt = 0; nt < 4; ++nt)
#pragma unroll
        for (int r = 0; r < 4; ++r) acc[nt][r] *= alpha;
      const bf16x8 pf0 = *(const bf16x8*)(&plds[wave][lr][lg * 8]);
      const bf16x8 pf1 = *(const bf16x8*)(&plds[wave][lr][32 + lg * 8]);
#pragma unroll
      for (int nt = 0; nt < 4; ++nt) {
        acc[nt] = __builtin_amdgcn_mfma_f32_16x16x32_bf16(vf[nt][0], pf0, acc[nt], 0, 0, 0);
        acc[nt] = __builtin_amdgcn_mfma_f32_16x16x32_bf16(vf[nt][1], pf1, acc[nt], 0, 0, 0);
      }
    }

    // ---- combine partials across the 8 waves
    __syncthreads();
#pragma unroll
    for (int nt = 0; nt < 4; ++nt)
      *(f32x4*)(&red_acc[wave][lane][nt * 4]) = acc[nt];
    if (lg == 0) {
      red_ml[wave][lr][0] = m;
      red_ml[wave][lr][1] = l;
    }
    __syncthreads();

    if (wave < 4) {  // wave v -> h-block v; lane (lr,lg): q=lr, h=v*16+lg*4+r
      float mw[8];
#pragma unroll
      for (int w2 = 0; w2 < 8; ++w2) mw[w2] = red_ml[w2][lr][0];
      float M = fmaxf(fmaxf(fmaxf(mw[0], mw[1]), fmaxf(mw[2], mw[3])),
                      fmaxf(fmaxf(mw[4], mw[5]), fmaxf(mw[6], mw[7])));
      float L = 0.f;
      f32x4 o = f32x4{0.f, 0.f, 0.f, 0.f};
#pragma unroll
      for (int w2 = 0; w2 < 8; ++w2) {
        const float e = __expf(mw[w2] - M);
        L += e * red_ml[w2][lr][1];
        const f32x4 a = *(const f32x4*)(&red_acc[w2][lane][wave * 4]);
        o[0] += e * a[0]; o[1] += e * a[1];
        o[2] += e * a[2]; o[3] += e * a[3];
      }
      const float invL = 1.0f / L;
      f32x4 res;
      res[0] = o[0] * invL; res[1] = o[1] * invL;
      res[2] = o[2] * invL; res[3] = o[3] * invL;
      *(f32x4*)(&out[(size_t)(b * T + q0 + lr) * H + wave * 16 + lg * 4]) = res;
    }
  }
}

// ---------------------------------------------------------------------------
extern "C" void kernel_launch(void* const* d_in, const int* in_sizes, int n_in,
                              void* d_out, int out_size, void* d_ws,
                              size_t ws_size, hipStream_t stream) {
  const float* x = (const float*)d_in[0];
  const float* Wk = (const float*)d_in[1];
  const float* Wq = (const float*)d_in[2];
  const float* Wv = (const float*)d_in[3];
  float* out = (float*)d_out;
  char* ws = (char*)d_ws;
  const size_t SZ = (size_t)B * T * H * sizeof(bf16_t);  // 2 MB each
  bf16_t* qb = (bf16_t*)ws;
  bf16_t* kb = (bf16_t*)(ws + SZ);
  bf16_t* vT = (bf16_t*)(ws + 2 * SZ);
  bf16_t* WT = (bf16_t*)(ws + 3 * SZ);  // 384 KB

  wconv_kernel<<<(3 * H * C + 255) / 256, 256, 0, stream>>>(Wk, Wq, Wv, WT);
  proj_kernel<<<(B * T) / 64, 256, 0, stream>>>(x, WT, qb, kb, vT);
  flash_kernel<<<dim3(B * T / 32), 512, 0, stream>>>(qb, kb, vT, out);
}